// Round 5
// baseline (337.935 us; speedup 1.0000x reference)
//
#include <hip/hip_runtime.h>
#include <cstdint>

#define N_ITER 64
#define N_CH 256
#define BATCH 4096
#define OUT_PLANE (BATCH * N_CH) /* 1048576 floats per output tensor */

typedef float v4f __attribute__((ext_vector_type(4)));
typedef int   v4i __attribute__((ext_vector_type(4)));
typedef float v2f __attribute__((ext_vector_type(2)));

// Exact replication of the fp32 reference's PrecisionSplit.
// For negative y, y_u = y + 2^25 lands where fp32 ulp = 2; odd y is an exact
// tie and round-half-even snaps to the nearest multiple of 4:
//   y ≡ 1 (mod 4) -> u-1 ;  y ≡ 3 (mod 4) -> u+1   (else exact)
// Then lo = u' & 0xFFF, hi = ((u'>>12 + 4096) & 8191) - 4096 (exact in fp32,
// including the u' = 2^25 corner -> (0,0)). Returns {lo, hi}.
__device__ __forceinline__ v2f split_ref_fp32(int y) {
    uint32_t u;
    if (y >= 0) {
        u = (uint32_t)y;
    } else {
        u = (uint32_t)(y + 33554432); // y + 2^25
        int m = y & 3;
        if (m == 1)      u -= 1u;
        else if (m == 3) u += 1u;
    }
    v2f r;
    r.x = (float)(u & 0xFFFu);
    int q = (int)(u >> 12);
    r.y = (float)(((q + 4096) & 8191) - 4096);
    return r;
}

// K1: pure streaming partial-sum. 2048 blocks x 256 = 8192 waves = exactly
// 32 waves/CU, single dispatch pass. Wave W owns half-row (row=W>>1, half=W&1):
// 32 iterations x 1 KiB coalesced NT loads, int32 accumulate (exact, assoc.),
// one 1 KiB partial store. No LDS, no barriers, no inter-wave coupling ->
// continuous outstanding-VMEM stream. Outer loop x4 / inner unroll 8 keeps
// ~8 loads in flight per wave at modest VGPR (occupancy stays 8 waves/SIMD).
__global__ __launch_bounds__(256) void i24_partial_kernel(const float* __restrict__ x,
                                                          int* __restrict__ ws) {
    const int tid  = threadIdx.x;
    const int lane = tid & 63;
    const int wave = tid >> 6;
    const int W    = blockIdx.x * 4 + wave;   // [0, 8192)
    const int row  = W >> 1;
    const int half = W & 1;

    const v4f* xr = reinterpret_cast<const v4f*>(x)
                  + (size_t)row * (N_ITER * N_CH / 4)
                  + (size_t)half * (32 * N_CH / 4);

    v4i acc = (v4i)0;
    for (int j = 0; j < 4; ++j) {
#pragma unroll
        for (int k = 0; k < 8; ++k) {
            v4f v = __builtin_nontemporal_load(xr + (j * 8 + k) * (N_CH / 4) + lane);
            acc.x += (int)rintf(v.x);  // rintf = round-half-even, matches jnp.round
            acc.y += (int)rintf(v.y);
            acc.z += (int)rintf(v.z);
            acc.w += (int)rintf(v.w);
        }
    }

    // partials layout: [4096 rows][2 halves][64 lanes] of v4i  (8 MiB)
    reinterpret_cast<v4i*>(ws)[(size_t)W * 64 + lane] = acc;
}

// K2: reduce 2 partials/row + s_init, sign-extend to int24, fp32-tie split.
// 1024 blocks x 256; wave w of block b -> row 4b+w; lane l -> ch 4l..4l+3.
// Traffic: 8 MiB read + 8 MiB write + 1 KiB.
__global__ __launch_bounds__(256) void i24_split_kernel(const int* __restrict__ ws,
                                                        const float* __restrict__ s_init,
                                                        float* __restrict__ out) {
    const int tid  = threadIdx.x;
    const int lane = tid & 63;
    const int wave = tid >> 6;
    const int row  = blockIdx.x * 4 + wave;

    const v4i* p = reinterpret_cast<const v4i*>(ws) + (size_t)row * 128; // 2*64
    v4i t = p[lane];
    t += p[64 + lane];

    const v4f s4 = reinterpret_cast<const v4f*>(s_init)[lane];
    t.x += (int)rintf(s4.x);
    t.y += (int)rintf(s4.y);
    t.z += (int)rintf(s4.z);
    t.w += (int)rintf(s4.w);

    // sign-extend to int24 domain (identity for this data — no wrap occurs,
    // |sums| << 2^23; kept for semantic fidelity to the mod-2^24 scan)
    t.x = (t.x << 8) >> 8;
    t.y = (t.y << 8) >> 8;
    t.z = (t.z << 8) >> 8;
    t.w = (t.w << 8) >> 8;

    const v2f sx = split_ref_fp32(t.x);
    const v2f sy = split_ref_fp32(t.y);
    const v2f sz = split_ref_fp32(t.z);
    const v2f sw = split_ref_fp32(t.w);

    v4f lo4, hi4;
    lo4.x = sx.x; hi4.x = sx.y;
    lo4.y = sy.x; hi4.y = sy.y;
    lo4.z = sz.x; hi4.z = sz.y;
    lo4.w = sw.x; hi4.w = sw.y;

    const int ovec = row * (N_CH / 4) + lane;  // v4f index within plane
    reinterpret_cast<v4f*>(out)[ovec] = lo4;
    reinterpret_cast<v4f*>(out + OUT_PLANE)[ovec] = hi4;
}

extern "C" void kernel_launch(void* const* d_in, const int* in_sizes, int n_in,
                              void* d_out, int out_size, void* d_ws, size_t ws_size,
                              hipStream_t stream) {
    const float* x      = (const float*)d_in[0];
    const float* s_init = (const float*)d_in[1];
    float*       out    = (float*)d_out;
    int*         ws     = (int*)d_ws;   // 8 MiB of partials

    i24_partial_kernel<<<dim3(2048), dim3(256), 0, stream>>>(x, ws);
    i24_split_kernel<<<dim3(1024), dim3(256), 0, stream>>>(ws, s_init, out);
}